// Round 5
// baseline (299.314 us; speedup 1.0000x reference)
//
#include <hip/hip_runtime.h>

#define BN     64
#define KCLS   3
#define PPIX   147456
#define NB1    4096
#define NB3    128

// ---- k_sample ----
#define NRUNS  4
#define RUNF4  512               // 2048 px per run
#define NSAMP  8192              // sampled px per row
#define MARGIN 520.0f            // ~16 sigma in sampled-rank units

// ---- k_stream ----
#define BPR    72                // blocks per row
#define F4BLK  512               // 2048 px per block
#define CAP    32768             // candidate cap per row (expected ~20K)

// ---------------- workspace layout (bytes) ----------------
static const size_t OFF_CAND = 0;                                  // BN*CAP*4 = 8 MB
static const size_t OFF_BL   = OFF_CAND + (size_t)BN * CAP * 4;
static const size_t OFF_BH   = OFF_BL + 256;
static const size_t OFF_CCNT = OFF_BH + 256;
static const size_t OFF_CHI  = OFF_CCNT + 256;
static const size_t OFF_SS   = OFF_CHI + 256;                      // double[64]
static const size_t OFF_ACC  = OFF_SS + 512;                       // double

__device__ __forceinline__ unsigned topk_count(const int* sp_ptr) {
    double sp = (double)sp_ptr[0];
    if (sp > 1.0) sp = 1.0;
    return (unsigned)(sp * 0.15 * (double)PPIX + (1.0 - sp) * (double)PPIX);
}

__device__ __forceinline__ float sel_nll(int t, float a, float b, float c) {
    float lp = (t == 0) ? a : ((t == 1) ? b : ((t == 2) ? c : 0.0f));
    return fmaxf(-lp, 0.0f);   // nll >= 0; kill -0.0
}

// ---------------- kernel 1: sampled histogram -> bracket [bL,bH]; zero state
__global__ __launch_bounds__(256) void k_sample(
    const float* __restrict__ in, const int* __restrict__ tgt, const int* __restrict__ sp,
    int* __restrict__ st_bL, int* __restrict__ st_bH,
    int* __restrict__ ccnt, unsigned* __restrict__ chi,
    double* __restrict__ st_S, double* __restrict__ accum)
{
    __shared__ unsigned hist[NB1];
    __shared__ unsigned csum[256];
    __shared__ int s_bL, s_bH;
    const int tid = threadIdx.x;
    const int row = blockIdx.x;

    for (int i = tid; i < NB1; i += 256) hist[i] = 0u;
    if (tid == 0) { s_bL = 0; s_bH = NB1 - 1; }
    __syncthreads();

    const float4* p0 = (const float4*)(in + (size_t)row * KCLS * PPIX);
    const float4* p1 = p0 + PPIX / 4;
    const float4* p2 = p1 + PPIX / 4;
    const int4*   t4 = (const int4*)(tgt + (size_t)row * PPIX);

    #pragma unroll
    for (int r = 0; r < NRUNS; ++r) {
        #pragma unroll
        for (int jj = 0; jj < RUNF4 / 256; ++jj) {
            const int g = r * (PPIX / 4 / NRUNS) + jj * 256 + tid;
            const int4   t = t4[g];
            const float4 a = p0[g];
            const float4 b = p1[g];
            const float4 c = p2[g];
            float v[4];
            v[0] = sel_nll(t.x, a.x, b.x, c.x);
            v[1] = sel_nll(t.y, a.y, b.y, c.y);
            v[2] = sel_nll(t.z, a.z, b.z, c.z);
            v[3] = sel_nll(t.w, a.w, b.w, c.w);
            #pragma unroll
            for (int q = 0; q < 4; ++q) atomicAdd(&hist[__float_as_uint(v[q]) >> 19], 1u);
        }
    }
    __syncthreads();

    // descending scan over sampled histogram
    unsigned cl[16]; unsigned cacc = 0;
    const int b0 = tid * 16;
    #pragma unroll
    for (int i = 0; i < 16; ++i) {
        cl[i] = hist[NB1 - 1 - (b0 + i)];
        cacc += cl[i];
    }
    csum[tid] = cacc;
    __syncthreads();
    for (int off = 1; off < 256; off <<= 1) {
        unsigned t2 = (tid >= off) ? csum[tid - off] : 0u;
        __syncthreads();
        csum[tid] += t2;
        __syncthreads();
    }

    const unsigned k = topk_count(sp);
    const float ks = (float)k * ((float)NSAMP / (float)PPIX);   // sampled-rank of k
    const float tH = ks - MARGIN;
    const float tL = ks + MARGIN;
    unsigned cum = tid ? csum[tid - 1] : 0u;
    #pragma unroll
    for (int i = 0; i < 16; ++i) {
        const unsigned cb = cl[i];
        const float fc = (float)cum, fe = (float)(cum + cb);
        if (fc < tH && fe >= tH) s_bH = NB1 - 1 - (b0 + i);
        if (fc < tL && fe >= tL) s_bL = NB1 - 1 - (b0 + i);
        cum += cb;
    }
    __syncthreads();
    if (tid == 0) {
        st_bL[row] = s_bL;
        st_bH[row] = s_bH;
        ccnt[row]  = 0;
        chi[row]   = 0u;
        st_S[row]  = 0.0;
        if (row == 0) accum[0] = 0.0;
    }
}

// ---------------- kernel 2: streaming sum-above + bracket compact -----------
__global__ __launch_bounds__(256) void k_stream(
    const float* __restrict__ in, const int* __restrict__ tgt,
    const int* __restrict__ st_bL, const int* __restrict__ st_bH,
    float* __restrict__ cand, int* __restrict__ ccnt,
    unsigned* __restrict__ chi, double* __restrict__ st_S)
{
    __shared__ float    stage[F4BLK * 4];   // 8 KB, worst case all candidates
    __shared__ double   dred[256];
    __shared__ unsigned cred[256];
    __shared__ int lcnt, gbase;
    const int tid = threadIdx.x;
    if (tid == 0) lcnt = 0;
    __syncthreads();

    const int row   = blockIdx.x / BPR;
    const int chunk = blockIdx.x % BPR;
    const unsigned lo = ((unsigned)st_bL[row]) << 19;
    const unsigned hi = ((unsigned)st_bH[row] + 1u) << 19;   // bH=4095 -> 0x80000000 -> nothing definite
    const float4* p0 = (const float4*)(in + (size_t)row * KCLS * PPIX);
    const float4* p1 = p0 + PPIX / 4;
    const float4* p2 = p1 + PPIX / 4;
    const int4*   t4 = (const int4*)(tgt + (size_t)row * PPIX);
    const int base = chunk * F4BLK;

    float facc = 0.0f; unsigned c = 0;
    #pragma unroll
    for (int j = 0; j < F4BLK / 256; ++j) {
        const int idx = base + j * 256 + tid;
        const int4   t = t4[idx];
        const float4 a = p0[idx];
        const float4 b = p1[idx];
        const float4 cc = p2[idx];
        float v[4];
        v[0] = sel_nll(t.x, a.x, b.x, cc.x);
        v[1] = sel_nll(t.y, a.y, b.y, cc.y);
        v[2] = sel_nll(t.z, a.z, b.z, cc.z);
        v[3] = sel_nll(t.w, a.w, b.w, cc.w);
        #pragma unroll
        for (int q = 0; q < 4; ++q) {
            const unsigned u = __float_as_uint(v[q]);
            if (u >= hi) {
                facc += v[q]; ++c;
            } else if (u >= lo) {
                const int s = atomicAdd(&lcnt, 1);
                stage[s] = v[q];
            }
        }
    }
    dred[tid] = (double)facc;
    cred[tid] = c;
    __syncthreads();
    for (int s = 128; s > 0; s >>= 1) {
        if (tid < s) { dred[tid] += dred[tid + s]; cred[tid] += cred[tid + s]; }
        __syncthreads();
    }
    if (tid == 0) {
        if (dred[0] != 0.0) atomicAdd(&st_S[row], dred[0]);
        if (cred[0])        atomicAdd(&chi[row], cred[0]);
        gbase = atomicAdd(&ccnt[row], lcnt);
    }
    __syncthreads();
    const int n = lcnt, gb = gbase;
    float* cr = cand + (size_t)row * CAP;
    for (int i = tid; i < n; i += 256) {
        const int pos = gb + i;
        if (pos < CAP) cr[pos] = stage[i];
    }
}

// ---------------- kernel 3: exact 3-level radix over candidates -------------
__global__ __launch_bounds__(256) void k_resolve(
    const float* __restrict__ cand, const int* __restrict__ ccnt,
    const unsigned* __restrict__ chi, const int* __restrict__ sp,
    const double* __restrict__ st_S, double* __restrict__ accum)
{
    __shared__ unsigned lc[NB1];
    __shared__ float    ls[NB1];
    __shared__ unsigned csum[256];
    __shared__ double   ssum[256];
    __shared__ int sbA, srA; __shared__ double sSA;
    __shared__ int sbB, srB; __shared__ double sSB;

    const int row = blockIdx.x, tid = threadIdx.x;
    int n = ccnt[row]; if (n > CAP) n = CAP;
    const float* cv = cand + (size_t)row * CAP;
    int kA = (int)topk_count(sp) - (int)chi[row];
    if (kA < 1) kA = 1;
    if (kA > n) kA = n;

    // ---- level A: bins = bits[30:19] ----
    for (int i = tid; i < NB1; i += 256) { lc[i] = 0u; ls[i] = 0.0f; }
    __syncthreads();
    for (int i = tid; i < n; i += 256) {
        const float v = cv[i];
        const unsigned key = __float_as_uint(v) >> 19;
        atomicAdd(&lc[key], 1u);
        atomicAdd(&ls[key], v);
    }
    __syncthreads();
    {
        unsigned cl[16]; float slv[16];
        unsigned cacc = 0; double sacc = 0.0;
        const int b0 = tid * 16;
        #pragma unroll
        for (int i = 0; i < 16; ++i) {
            const int bin = NB1 - 1 - (b0 + i);
            cl[i] = lc[bin]; slv[i] = ls[bin];
            cacc += cl[i]; sacc += (double)slv[i];
        }
        csum[tid] = cacc; ssum[tid] = sacc;
        __syncthreads();
        for (int off = 1; off < 256; off <<= 1) {
            unsigned c2 = 0; double s2 = 0.0;
            if (tid >= off) { c2 = csum[tid - off]; s2 = ssum[tid - off]; }
            __syncthreads();
            csum[tid] += c2; ssum[tid] += s2;
            __syncthreads();
        }
        int cum = tid ? (int)csum[tid - 1] : 0;
        double sS = tid ? ssum[tid - 1] : 0.0;
        #pragma unroll
        for (int i = 0; i < 16; ++i) {
            const int cb = (int)cl[i];
            if (cum < kA && cum + cb >= kA) {
                sbA = NB1 - 1 - (b0 + i);
                srA = kA - cum;
                sSA = sS;
            }
            cum += cb;
            sS  += (double)slv[i];
        }
    }
    __syncthreads();

    // ---- level B: among (u>>19)==bA, bins = bits[18:7] ----
    const unsigned bA = (unsigned)sbA;
    const int kB = srA;
    __syncthreads();
    for (int i = tid; i < NB1; i += 256) { lc[i] = 0u; ls[i] = 0.0f; }
    __syncthreads();
    for (int i = tid; i < n; i += 256) {
        const float v = cv[i];
        const unsigned u = __float_as_uint(v);
        if ((u >> 19) == bA) {
            const unsigned key = (u >> 7) & 0xFFFu;
            atomicAdd(&lc[key], 1u);
            atomicAdd(&ls[key], v);
        }
    }
    __syncthreads();
    {
        unsigned cl[16]; float slv[16];
        unsigned cacc = 0; double sacc = 0.0;
        const int b0 = tid * 16;
        #pragma unroll
        for (int i = 0; i < 16; ++i) {
            const int bin = NB1 - 1 - (b0 + i);
            cl[i] = lc[bin]; slv[i] = ls[bin];
            cacc += cl[i]; sacc += (double)slv[i];
        }
        csum[tid] = cacc; ssum[tid] = sacc;
        __syncthreads();
        for (int off = 1; off < 256; off <<= 1) {
            unsigned c2 = 0; double s2 = 0.0;
            if (tid >= off) { c2 = csum[tid - off]; s2 = ssum[tid - off]; }
            __syncthreads();
            csum[tid] += c2; ssum[tid] += s2;
            __syncthreads();
        }
        int cum = tid ? (int)csum[tid - 1] : 0;
        double sS = tid ? ssum[tid - 1] : 0.0;
        #pragma unroll
        for (int i = 0; i < 16; ++i) {
            const int cb = (int)cl[i];
            if (cum < kB && cum + cb >= kB) {
                sbB = NB1 - 1 - (b0 + i);
                srB = kB - cum;
                sSB = sS;
            }
            cum += cb;
            sS  += (double)slv[i];
        }
    }
    __syncthreads();

    // ---- level C: prefix bits[30:7], bins = bits[6:0] ----
    const unsigned pref = (bA << 12) | (unsigned)sbB;
    const int kC = srB;
    __syncthreads();
    if (tid < NB3) { lc[tid] = 0u; ls[tid] = 0.0f; }
    __syncthreads();
    for (int i = tid; i < n; i += 256) {
        const float v = cv[i];
        const unsigned u = __float_as_uint(v);
        if ((u >> 7) == pref) {
            atomicAdd(&lc[u & 0x7Fu], 1u);
            atomicAdd(&ls[u & 0x7Fu], v);
        }
    }
    __syncthreads();
    if (tid == 0) {
        int cum = 0, r3 = 0, b3 = 0; double S3 = 0.0;
        for (int bin = NB3 - 1; bin >= 0; --bin) {
            const int cb = (int)lc[bin];
            if (cum < kC && cum + cb >= kC) { b3 = bin; r3 = kC - cum; break; }
            cum += cb;
            S3  += (double)ls[bin];
        }
        const float tval = __uint_as_float((pref << 7) | (unsigned)b3);
        const double total = st_S[row] + sSA + sSB + S3 + (double)r3 * (double)tval;
        atomicAdd(accum, total);
    }
}

// ---------------- kernel 4: write mean --------------------------------------
__global__ void k_out(const double* __restrict__ accum, const int* __restrict__ sp_ptr,
                      float* __restrict__ out)
{
    if (threadIdx.x == 0 && blockIdx.x == 0) {
        const unsigned k = topk_count(sp_ptr);
        out[0] = (float)(accum[0] / ((double)BN * (double)k));
    }
}

extern "C" void kernel_launch(void* const* d_in, const int* in_sizes, int n_in,
                              void* d_out, int out_size, void* d_ws, size_t ws_size,
                              hipStream_t stream)
{
    const float* in  = (const float*)d_in[0];
    const int*   tgt = (const int*)d_in[1];
    const int*   sp  = (const int*)d_in[2];

    char* ws = (char*)d_ws;
    float*    cand  = (float*)(ws + OFF_CAND);
    int*      st_bL = (int*)(ws + OFF_BL);
    int*      st_bH = (int*)(ws + OFF_BH);
    int*      ccnt  = (int*)(ws + OFF_CCNT);
    unsigned* chi   = (unsigned*)(ws + OFF_CHI);
    double*   st_S  = (double*)(ws + OFF_SS);
    double*   accum = (double*)(ws + OFF_ACC);

    k_sample <<<BN, 256, 0, stream>>>(in, tgt, sp, st_bL, st_bH, ccnt, chi, st_S, accum);
    k_stream <<<BN * BPR, 256, 0, stream>>>(in, tgt, st_bL, st_bH, cand, ccnt, chi, st_S);
    k_resolve<<<BN, 256, 0, stream>>>(cand, ccnt, chi, sp, st_S, accum);
    k_out    <<<1, 64, 0, stream>>>(accum, sp, (float*)d_out);
}